// Round 2
// baseline (892.445 us; speedup 1.0000x reference)
//
#include <hip/hip_runtime.h>
#include <hip/hip_bf16.h>

#define BB  8
#define HIDC 128
#define INPC 320
#define CC  448
#define HH  64
#define WWI 128
#define HW  8192   // 64*128

using bf16   = __hip_bfloat16;
using bf16x8 = __attribute__((ext_vector_type(8))) __bf16;
using f32x4  = __attribute__((ext_vector_type(4))) float;

__device__ __forceinline__ float b2f(bf16 v) { return __bfloat162float(v); }
__device__ __forceinline__ bf16  f2b(float v) { return __float2bfloat16(v); }
__device__ __forceinline__ float ldv(float v) { return v; }
__device__ __forceinline__ float ldv(bf16 v)  { return b2f(v); }

// ---------------- per-tensor symmetric int8 fake-quant ----------------
// scale = max(max|w|,1e-8)/127 ; q = clip(rint(w/scale),-128,127)
// dw gates: store q*scale as f32. pw gates: store q as bf16 INTEGER (exact),
// scale applied in the GEMM epilogue -> no bf16 rounding on weights.
__global__ __launch_bounds__(256) void quant_kernel(
    const float* wdz, const float* wpz, const float* wdr, const float* wpr,
    const float* wdq, const float* wpq, float* qwd, bf16* qwp, float* scales)
{
  const float* src = nullptr; int n = 0; float* df = nullptr; bf16* db = nullptr;
  int sidx = -1;
  switch (blockIdx.x) {
    case 0: src = wdz; n = CC * 9;    df = qwd;                 break;
    case 1: src = wpz; n = HIDC * CC; db = qwp;                 sidx = 0; break;
    case 2: src = wdr; n = CC * 9;    df = qwd + 4096;          break;
    case 3: src = wpr; n = HIDC * CC; db = qwp + HIDC * CC;     sidx = 1; break;
    case 4: src = wdq; n = CC * 9;    df = qwd + 8192;          break;
    case 5: src = wpq; n = HIDC * CC; db = qwp + 2 * HIDC * CC; sidx = 2; break;
  }
  __shared__ float red[256];
  int tid = threadIdx.x;
  float m = 0.f;
  for (int i = tid; i < n; i += 256) m = fmaxf(m, fabsf(src[i]));
  red[tid] = m; __syncthreads();
  for (int s = 128; s > 0; s >>= 1) {
    if (tid < s) red[tid] = fmaxf(red[tid], red[tid + s]);
    __syncthreads();
  }
  float scale = fmaxf(red[0], 1e-8f) / 127.f;
  if (sidx >= 0 && tid == 0) scales[sidx] = scale;
  for (int i = tid; i < n; i += 256) {
    float q = rintf(src[i] / scale);             // RNE, matches jnp.round
    q = fminf(fmaxf(q, -128.f), 127.f);
    if (df) df[i] = q * scale;
    else    db[i] = f2b(q);                      // integer in [-128,127]: exact in bf16
  }
}

// ---------------- depthwise 3x3 SAME (f32 math), NCHW in -> NHWC bf16 out ----
// NG=2: two gates (z,r) share the input read. NG=1: q gate.
template <int NG, typename TH>
__global__ __launch_bounds__(256) void dwconv_kernel(
    const TH*    __restrict__ src_h,   // 128-ch tensor (h f32 or r*h bf16), NCHW
    const float* __restrict__ src_x,   // 320-ch tensor x, NCHW
    const float* __restrict__ w0, const float* __restrict__ b0,
    const float* __restrict__ w1, const float* __restrict__ b1,
    bf16* __restrict__ out0, bf16* __restrict__ out1)   // NHWC [B*HW][448]
{
  int cg = blockIdx.x;                   // 0..55  (8 channels each)
  int b  = blockIdx.z;                   // 0..7
  int y  = blockIdx.y * 2 + (threadIdx.x >> 7);
  int x  = threadIdx.x & 127;
  int c0 = cg * 8;
  bool in_h = (c0 < HIDC);
  const TH*    baseh = src_h + ((size_t)b * HIDC + c0) * HW;
  const float* basex = src_x + ((size_t)b * INPC + (c0 - HIDC)) * HW;
  float acc0[8], acc1[8];
#pragma unroll
  for (int i = 0; i < 8; i++) {
    int c = c0 + i;
    const TH*    planeh = baseh + (size_t)i * HW;
    const float* planex = basex + (size_t)i * HW;
    float a0 = 0.f, a1 = 0.f;
#pragma unroll
    for (int dy = -1; dy <= 1; dy++) {
      int yy = y + dy;
      if ((unsigned)yy < (unsigned)HH) {
#pragma unroll
        for (int dx = -1; dx <= 1; dx++) {
          int xx = x + dx;
          if ((unsigned)xx < (unsigned)WWI) {
            float v = in_h ? ldv(planeh[yy * WWI + xx]) : planex[yy * WWI + xx];
            int wi = c * 9 + (dy + 1) * 3 + (dx + 1);
            a0 += v * w0[wi];
            if (NG == 2) a1 += v * w1[wi];
          }
        }
      }
    }
    acc0[i] = a0 + b0[c];
    if (NG == 2) acc1[i] = a1 + b1[c];
  }
  size_t pix = (size_t)b * HW + (size_t)y * WWI + x;
  bf16x8 v0, v1;
#pragma unroll
  for (int i = 0; i < 8; i++) {
    v0[i] = (__bf16)acc0[i];
    if (NG == 2) v1[i] = (__bf16)acc1[i];
  }
  *reinterpret_cast<bf16x8*>(out0 + pix * CC + c0) = v0;
  if (NG == 2) *reinterpret_cast<bf16x8*>(out1 + pix * CC + c0) = v1;
}

// ---------------- pointwise 448->128 as MFMA GEMM + fused epilogue ----------
// pre = (sum_k q_int[o][k]*d[n][k]) * scale + bias[o]
// GATE 0: z = sigmoid(pre) -> zout (f32)
// GATE 1: r = sigmoid(pre) ; rhout = bf16(r * h)
// GATE 2: q = tanh(pre)    ; qout  = f32((1-z)*h + z*q)
template <int GATE>
__global__ __launch_bounds__(256) void pw_kernel(
    const bf16*  __restrict__ dbuf,   // NHWC [B*HW][448] bf16
    const bf16*  __restrict__ wp,     // [128][448] int8 values as bf16
    const float* __restrict__ bp,     // [128] f32
    const float* __restrict__ scale_p,
    const float* __restrict__ h,      // NCHW f32
    const float* __restrict__ zin,    // f32 (GATE==2)
    float* __restrict__ zout,         // GATE==0
    bf16*  __restrict__ rhout,        // GATE==1
    float* __restrict__ qout)         // GATE==2
{
  __shared__ bf16 Blds[128 * 40];    // n-major, stride 40 elems (80 B, 16B-aligned frags)
  int b    = blockIdx.y;
  int n0   = blockIdx.x * 128;
  int tid  = threadIdx.x;
  int wave = tid >> 6;
  int lane = tid & 63;
  int quad = lane >> 4;
  int lr   = lane & 15;
  int m0   = wave * 32;              // each wave: 32 M-rows x 128 N
  f32x4 acc[2][8] = {};
  const bf16* dbase = dbuf + ((size_t)b * HW + n0) * CC;
  float s = *scale_p;

  for (int kk = 0; kk < 14; kk++) {
    int k0 = kk * 32;
    // stage B tile: 128 n x 32 k
#pragma unroll
    for (int it = 0; it < 2; it++) {
      int cidx = tid + it * 256;            // 0..511
      int n = cidx >> 2, kg = cidx & 3;
      bf16x8 g = *reinterpret_cast<const bf16x8*>(dbase + (size_t)n * CC + k0 + kg * 8);
      *reinterpret_cast<bf16x8*>(&Blds[n * 40 + kg * 8]) = g;
    }
    __syncthreads();
    // A frags straight from global (weights 112 KB total, L2-hot)
    bf16x8 a0 = *reinterpret_cast<const bf16x8*>(wp + (size_t)(m0 + lr) * CC + k0 + quad * 8);
    bf16x8 a1 = *reinterpret_cast<const bf16x8*>(wp + (size_t)(m0 + 16 + lr) * CC + k0 + quad * 8);
#pragma unroll
    for (int nf = 0; nf < 8; nf++) {
      bf16x8 bfr = *reinterpret_cast<const bf16x8*>(&Blds[(nf * 16 + lr) * 40 + quad * 8]);
      acc[0][nf] = __builtin_amdgcn_mfma_f32_16x16x32_bf16(a0, bfr, acc[0][nf], 0, 0, 0);
      acc[1][nf] = __builtin_amdgcn_mfma_f32_16x16x32_bf16(a1, bfr, acc[1][nf], 0, 0, 0);
    }
    __syncthreads();
  }

  // epilogue: C/D layout col = lane&15 (N), row = quad*4 + reg (M)
#pragma unroll
  for (int mf = 0; mf < 2; mf++) {
#pragma unroll
    for (int r = 0; r < 4; r++) {
      int o = m0 + mf * 16 + quad * 4 + r;
      float bias = bp[o];
#pragma unroll
      for (int nf = 0; nf < 8; nf++) {
        int n = n0 + nf * 16 + lr;
        size_t idx = ((size_t)b * HIDC + o) * HW + n;
        float pre = acc[mf][nf][r] * s + bias;
        if (GATE == 0) {
          zout[idx] = 1.f / (1.f + expf(-pre));
        } else if (GATE == 1) {
          float rv = 1.f / (1.f + expf(-pre));
          rhout[idx] = f2b(rv * h[idx]);
        } else {
          float qv = tanhf(pre);
          float zv = zin[idx];
          float hv = h[idx];
          qout[idx] = (1.f - zv) * hv + zv * qv;
        }
      }
    }
  }
}

extern "C" void kernel_launch(void* const* d_in, const int* in_sizes, int n_in,
                              void* d_out, int out_size, void* d_ws, size_t ws_size,
                              hipStream_t stream)
{
  const float* h   = (const float*)d_in[0];
  const float* x   = (const float*)d_in[1];
  const float* wdz = (const float*)d_in[2];
  const float* bdz = (const float*)d_in[3];
  const float* wpz = (const float*)d_in[4];
  const float* bpz = (const float*)d_in[5];
  const float* wdr = (const float*)d_in[6];
  const float* bdr = (const float*)d_in[7];
  const float* wpr = (const float*)d_in[8];
  const float* bpr = (const float*)d_in[9];
  const float* wdq = (const float*)d_in[10];
  const float* bdq = (const float*)d_in[11];
  const float* wpq = (const float*)d_in[12];
  const float* bpq = (const float*)d_in[13];

  char* ws = (char*)d_ws;
  float* qwd    = (float*)ws;                   // [0,4032) z | [4096,8128) r | [8192,12224) q
  float* scales = qwd + 12288;                  // 3 floats
  bf16*  qwp    = (bf16*)(ws + 65536);          // 3 x 57344 bf16 (int8 values)
  const size_t DBUF_ELEMS = (size_t)BB * HW * CC;      // 29,360,128
  bf16*  dz   = (bf16*)(ws + (1 << 20));                       // 58.7 MB
  bf16*  dr   = dz + DBUF_ELEMS;                               // 58.7 MB
  float* zbuf = (float*)((char*)(dr + DBUF_ELEMS));            // 33.5 MB
  bf16*  rh   = (bf16*)((char*)zbuf + (size_t)BB * HIDC * HW * sizeof(float)); // 16.8 MB

  quant_kernel<<<6, 256, 0, stream>>>(wdz, wpz, wdr, wpr, wdq, wpq, qwd, qwp, scales);

  dim3 dgrid(56, 32, 8);   // (cgroup, y-pair, batch)
  dwconv_kernel<2, float><<<dgrid, 256, 0, stream>>>(h, x, qwd, bdz, qwd + 4096, bdr, dz, dr);

  dim3 pgrid(64, 8);       // (n-tile, batch)
  pw_kernel<0><<<pgrid, 256, 0, stream>>>(dz, qwp, bpz, scales + 0, nullptr, nullptr,
                                          zbuf, nullptr, nullptr);
  pw_kernel<1><<<pgrid, 256, 0, stream>>>(dr, qwp + HIDC * CC, bpr, scales + 1, h, nullptr,
                                          nullptr, rh, nullptr);

  dwconv_kernel<1, bf16><<<dgrid, 256, 0, stream>>>(rh, x, qwd + 8192, bdq, nullptr, nullptr,
                                                    dz, nullptr);

  pw_kernel<2><<<pgrid, 256, 0, stream>>>(dz, qwp + 2 * HIDC * CC, bpq, scales + 2, h, zbuf,
                                          nullptr, nullptr, (float*)d_out);
}

// Round 3
// 758.449 us; speedup vs baseline: 1.1767x; 1.1767x over previous
//
#include <hip/hip_runtime.h>
#include <hip/hip_bf16.h>

#define BB  8
#define HIDC 128
#define INPC 320
#define CC  448
#define HH  64
#define WWI 128
#define HW  8192   // 64*128
#define NT_PER_B 512        // HW/16
#define KG  56              // CC/8
// frag-tiled dbuf: [b][nt][kg][ln(16)][kj(8)] bf16; elem off = ((b*512+nt)*56+kg)*128 + ln*8 + kj

using bf16   = __hip_bfloat16;
using bf16x8 = __attribute__((ext_vector_type(8))) __bf16;
using f32x4  = __attribute__((ext_vector_type(4))) float;

__device__ __forceinline__ float b2f(bf16 v) { return __bfloat162float(v); }
__device__ __forceinline__ bf16  f2b(float v) { return __float2bfloat16(v); }
__device__ __forceinline__ float ldv(float v) { return v; }
__device__ __forceinline__ float ldv(bf16 v)  { return b2f(v); }

// ---------------- per-tensor symmetric int8 fake-quant ----------------
// scale = max(max|w|,1e-8)/127 ; q = clip(rint(w/scale),-128,127)
// dw gates: store q*scale as f32. pw gates: store q as bf16 INTEGER (exact),
// scale applied in the GEMM epilogue -> no bf16 rounding on weights.
__global__ __launch_bounds__(256) void quant_kernel(
    const float* wdz, const float* wpz, const float* wdr, const float* wpr,
    const float* wdq, const float* wpq, float* qwd, bf16* qwp, float* scales)
{
  const float* src = nullptr; int n = 0; float* df = nullptr; bf16* db = nullptr;
  int sidx = -1;
  switch (blockIdx.x) {
    case 0: src = wdz; n = CC * 9;    df = qwd;                 break;
    case 1: src = wpz; n = HIDC * CC; db = qwp;                 sidx = 0; break;
    case 2: src = wdr; n = CC * 9;    df = qwd + 4096;          break;
    case 3: src = wpr; n = HIDC * CC; db = qwp + HIDC * CC;     sidx = 1; break;
    case 4: src = wdq; n = CC * 9;    df = qwd + 8192;          break;
    case 5: src = wpq; n = HIDC * CC; db = qwp + 2 * HIDC * CC; sidx = 2; break;
  }
  __shared__ float red[256];
  int tid = threadIdx.x;
  float m = 0.f;
  for (int i = tid; i < n; i += 256) m = fmaxf(m, fabsf(src[i]));
  red[tid] = m; __syncthreads();
  for (int s = 128; s > 0; s >>= 1) {
    if (tid < s) red[tid] = fmaxf(red[tid], red[tid + s]);
    __syncthreads();
  }
  float scale = fmaxf(red[0], 1e-8f) / 127.f;
  if (sidx >= 0 && tid == 0) scales[sidx] = scale;
  for (int i = tid; i < n; i += 256) {
    float q = rintf(src[i] / scale);             // RNE, matches jnp.round
    q = fminf(fmaxf(q, -128.f), 127.f);
    if (df) df[i] = q * scale;
    else    db[i] = f2b(q);                      // integer in [-128,127]: exact in bf16
  }
}

// ---------------- depthwise 3x3 SAME (f32 math), NCHW in -> frag-tiled bf16 --
// NG=2: two gates (z,r) share the input read. NG=1: q gate.
template <int NG, typename TH>
__global__ __launch_bounds__(256) void dwconv_kernel(
    const TH*    __restrict__ src_h,   // 128-ch tensor (h f32 or r*h bf16), NCHW
    const float* __restrict__ src_x,   // 320-ch tensor x, NCHW
    const float* __restrict__ w0, const float* __restrict__ b0,
    const float* __restrict__ w1, const float* __restrict__ b1,
    bf16* __restrict__ out0, bf16* __restrict__ out1)   // frag-tiled
{
  int cg = blockIdx.x;                   // 0..55  (8 channels each) == kg
  int b  = blockIdx.z;                   // 0..7
  int y  = blockIdx.y * 2 + (threadIdx.x >> 7);
  int x  = threadIdx.x & 127;
  int c0 = cg * 8;
  bool in_h = (c0 < HIDC);
  const TH*    baseh = src_h + ((size_t)b * HIDC + c0) * HW;
  const float* basex = src_x + ((size_t)b * INPC + (c0 - HIDC)) * HW;
  float acc0[8], acc1[8];
#pragma unroll
  for (int i = 0; i < 8; i++) {
    int c = c0 + i;
    const TH*    planeh = baseh + (size_t)i * HW;
    const float* planex = basex + (size_t)i * HW;
    float a0 = 0.f, a1 = 0.f;
#pragma unroll
    for (int dy = -1; dy <= 1; dy++) {
      int yy = y + dy;
      if ((unsigned)yy < (unsigned)HH) {
#pragma unroll
        for (int dx = -1; dx <= 1; dx++) {
          int xx = x + dx;
          if ((unsigned)xx < (unsigned)WWI) {
            float v = in_h ? ldv(planeh[yy * WWI + xx]) : planex[yy * WWI + xx];
            int wi = c * 9 + (dy + 1) * 3 + (dx + 1);
            a0 += v * w0[wi];
            if (NG == 2) a1 += v * w1[wi];
          }
        }
      }
    }
    acc0[i] = a0 + b0[c];
    if (NG == 2) acc1[i] = a1 + b1[c];
  }
  int pix = y * WWI + x;                 // within batch
  int nt = pix >> 4, ln = pix & 15;
  size_t off = (((size_t)b * NT_PER_B + nt) * KG + cg) * 128 + ln * 8;
  bf16x8 v0, v1;
#pragma unroll
  for (int i = 0; i < 8; i++) {
    v0[i] = (__bf16)acc0[i];
    if (NG == 2) v1[i] = (__bf16)acc1[i];
  }
  *reinterpret_cast<bf16x8*>(out0 + off) = v0;
  if (NG == 2) *reinterpret_cast<bf16x8*>(out1 + off) = v1;
}

// ---------------- pointwise 448->128 as MFMA GEMM + fused epilogue ----------
// pre = (sum_k q_int[o][k]*d[n][k]) * scale + bias[o]
// GATE 0: z = sigmoid(pre) -> zout (f32)
// GATE 1: r = sigmoid(pre) ; rhout = bf16(r * h)
// GATE 2: q = tanh(pre)    ; qout  = f32((1-z)*h + z*q)
template <int GATE>
__global__ __launch_bounds__(256) void pw_kernel(
    const bf16*  __restrict__ dbuf,   // frag-tiled [b][nt][kg][16][8] bf16
    const bf16*  __restrict__ wp,     // [128][448] int8 values as bf16
    const float* __restrict__ bp,     // [128] f32
    const float* __restrict__ scale_p,
    const float* __restrict__ h,      // NCHW f32
    const float* __restrict__ zin,    // f32 (GATE==2)
    float* __restrict__ zout,         // GATE==0
    bf16*  __restrict__ rhout,        // GATE==1
    float* __restrict__ qout)         // GATE==2
{
  __shared__ bf16 Blds[4096];        // [nt(8)][kgl(4)][ln(16)][kj(8)] = 8 KB
  int b    = blockIdx.y;
  int n0   = blockIdx.x * 128;
  int nt0  = blockIdx.x * 8;
  int tid  = threadIdx.x;
  int wave = tid >> 6;
  int lane = tid & 63;
  int quad = lane >> 4;
  int lr   = lane & 15;
  int m0   = wave * 32;              // each wave: 32 M-rows x 128 N
  f32x4 acc[2][8] = {};
  const bf16* dbt = dbuf + ((size_t)b * NT_PER_B + nt0) * (KG * 128);
  float s = *scale_p;

  for (int kk = 0; kk < 14; kk++) {
    // stage B tile: 8 nt x 4 kgl x 128 elems, linear copy (no transpose)
#pragma unroll
    for (int it = 0; it < 2; it++) {
      int c = tid + it * 256;               // chunk id 0..511 (16 B each)
      int cell = c >> 4, sub = c & 15;      // cell = nt*4+kgl
      int nt = cell >> 2, kgl = cell & 3;
      bf16x8 g = *reinterpret_cast<const bf16x8*>(
          dbt + ((size_t)nt * KG + kk * 4 + kgl) * 128 + sub * 8);
      *reinterpret_cast<bf16x8*>(&Blds[c * 8]) = g;
    }
    __syncthreads();
    int k0 = kk * 32;
    // A frags straight from global (weights 112 KB total, L2-hot)
    bf16x8 a0 = *reinterpret_cast<const bf16x8*>(wp + (size_t)(m0 + lr) * CC + k0 + quad * 8);
    bf16x8 a1 = *reinterpret_cast<const bf16x8*>(wp + (size_t)(m0 + 16 + lr) * CC + k0 + quad * 8);
#pragma unroll
    for (int nf = 0; nf < 8; nf++) {
      bf16x8 bfr = *reinterpret_cast<const bf16x8*>(&Blds[((nf * 4 + quad) * 16 + lr) * 8]);
      acc[0][nf] = __builtin_amdgcn_mfma_f32_16x16x32_bf16(a0, bfr, acc[0][nf], 0, 0, 0);
      acc[1][nf] = __builtin_amdgcn_mfma_f32_16x16x32_bf16(a1, bfr, acc[1][nf], 0, 0, 0);
    }
    __syncthreads();
  }

  // epilogue: C/D layout col(N) = lane&15, row(M) = quad*4 + reg
#pragma unroll
  for (int mf = 0; mf < 2; mf++) {
#pragma unroll
    for (int r = 0; r < 4; r++) {
      int o = m0 + mf * 16 + quad * 4 + r;
      float bias = bp[o];
#pragma unroll
      for (int nf = 0; nf < 8; nf++) {
        int n = n0 + nf * 16 + lr;
        size_t idx = ((size_t)b * HIDC + o) * HW + n;
        float pre = acc[mf][nf][r] * s + bias;
        if (GATE == 0) {
          zout[idx] = 1.f / (1.f + expf(-pre));
        } else if (GATE == 1) {
          float rv = 1.f / (1.f + expf(-pre));
          rhout[idx] = f2b(rv * h[idx]);
        } else {
          float qv = tanhf(pre);
          float zv = zin[idx];
          float hv = h[idx];
          qout[idx] = (1.f - zv) * hv + zv * qv;
        }
      }
    }
  }
}

extern "C" void kernel_launch(void* const* d_in, const int* in_sizes, int n_in,
                              void* d_out, int out_size, void* d_ws, size_t ws_size,
                              hipStream_t stream)
{
  const float* h   = (const float*)d_in[0];
  const float* x   = (const float*)d_in[1];
  const float* wdz = (const float*)d_in[2];
  const float* bdz = (const float*)d_in[3];
  const float* wpz = (const float*)d_in[4];
  const float* bpz = (const float*)d_in[5];
  const float* wdr = (const float*)d_in[6];
  const float* bdr = (const float*)d_in[7];
  const float* wpr = (const float*)d_in[8];
  const float* bpr = (const float*)d_in[9];
  const float* wdq = (const float*)d_in[10];
  const float* bdq = (const float*)d_in[11];
  const float* wpq = (const float*)d_in[12];
  const float* bpq = (const float*)d_in[13];

  char* ws = (char*)d_ws;
  float* qwd    = (float*)ws;                   // [0,4032) z | [4096,8128) r | [8192,12224) q
  float* scales = qwd + 12288;                  // 3 floats
  bf16*  qwp    = (bf16*)(ws + 65536);          // 3 x 57344 bf16 (int8 values)
  const size_t DBUF_ELEMS = (size_t)BB * NT_PER_B * KG * 128;  // 29,360,128
  bf16*  dz   = (bf16*)(ws + (1 << 20));                       // 58.7 MB
  bf16*  dr   = dz + DBUF_ELEMS;                               // 58.7 MB
  float* zbuf = (float*)((char*)(dr + DBUF_ELEMS));            // 33.5 MB
  bf16*  rh   = (bf16*)((char*)zbuf + (size_t)BB * HIDC * HW * sizeof(float)); // 16.8 MB

  quant_kernel<<<6, 256, 0, stream>>>(wdz, wpz, wdr, wpr, wdq, wpq, qwd, qwp, scales);

  dim3 dgrid(56, 32, 8);   // (cgroup, y-pair, batch)
  dwconv_kernel<2, float><<<dgrid, 256, 0, stream>>>(h, x, qwd, bdz, qwd + 4096, bdr, dz, dr);

  dim3 pgrid(64, 8);       // (n-tile, batch)
  pw_kernel<0><<<pgrid, 256, 0, stream>>>(dz, qwp, bpz, scales + 0, nullptr, nullptr,
                                          zbuf, nullptr, nullptr);
  pw_kernel<1><<<pgrid, 256, 0, stream>>>(dr, qwp + HIDC * CC, bpr, scales + 1, h, nullptr,
                                          nullptr, rh, nullptr);

  dwconv_kernel<1, bf16><<<dgrid, 256, 0, stream>>>(rh, x, qwd + 8192, bdq, nullptr, nullptr,
                                                    dz, nullptr);

  pw_kernel<2><<<pgrid, 256, 0, stream>>>(dz, qwp + 2 * HIDC * CC, bpq, scales + 2, h, zbuf,
                                          nullptr, nullptr, (float*)d_out);
}

// Round 4
// 596.436 us; speedup vs baseline: 1.4963x; 1.2716x over previous
//
#include <hip/hip_runtime.h>
#include <hip/hip_bf16.h>

#define BB  8
#define HIDC 128
#define INPC 320
#define CC  448
#define HH  64
#define WWI 128
#define HW  8192   // 64*128
#define NT_PER_B 512        // HW/16
#define KG  56              // CC/8
// frag-tiled dbuf: [b][nt][kg][ln(16)][kj(8)] bf16; elem off = ((b*512+nt)*56+kg)*128 + ln*8 + kj

using bf16   = __hip_bfloat16;
using bf16x8 = __attribute__((ext_vector_type(8))) __bf16;
using bf16x4 = __attribute__((ext_vector_type(4))) __bf16;
using f32x4  = __attribute__((ext_vector_type(4))) float;

__device__ __forceinline__ float b2f(bf16 v) { return __bfloat162float(v); }
__device__ __forceinline__ bf16  f2b(float v) { return __float2bfloat16(v); }

__device__ __forceinline__ void load4(const float* p, float v[4]) {
  f32x4 t = *reinterpret_cast<const f32x4*>(p);     // 16B-aligned (x0 mult of 4)
  v[0] = t[0]; v[1] = t[1]; v[2] = t[2]; v[3] = t[3];
}
__device__ __forceinline__ void load4(const bf16* p, float v[4]) {
  bf16x4 t = *reinterpret_cast<const bf16x4*>(p);   // 8B-aligned
  v[0] = (float)t[0]; v[1] = (float)t[1]; v[2] = (float)t[2]; v[3] = (float)t[3];
}

// ---------------- per-tensor symmetric int8 fake-quant ----------------
// scale = max(max|w|,1e-8)/127 ; q = clip(rint(w/scale),-128,127)
// dw gates: store q*scale as f32. pw gates: store q as bf16 INTEGER (exact),
// scale applied in the GEMM epilogue -> no bf16 rounding on weights.
__global__ __launch_bounds__(256) void quant_kernel(
    const float* wdz, const float* wpz, const float* wdr, const float* wpr,
    const float* wdq, const float* wpq, float* qwd, bf16* qwp, float* scales)
{
  const float* src = nullptr; int n = 0; float* df = nullptr; bf16* db = nullptr;
  int sidx = -1;
  switch (blockIdx.x) {
    case 0: src = wdz; n = CC * 9;    df = qwd;                 break;
    case 1: src = wpz; n = HIDC * CC; db = qwp;                 sidx = 0; break;
    case 2: src = wdr; n = CC * 9;    df = qwd + 4096;          break;
    case 3: src = wpr; n = HIDC * CC; db = qwp + HIDC * CC;     sidx = 1; break;
    case 4: src = wdq; n = CC * 9;    df = qwd + 8192;          break;
    case 5: src = wpq; n = HIDC * CC; db = qwp + 2 * HIDC * CC; sidx = 2; break;
  }
  __shared__ float red[256];
  int tid = threadIdx.x;
  float m = 0.f;
  for (int i = tid; i < n; i += 256) m = fmaxf(m, fabsf(src[i]));
  red[tid] = m; __syncthreads();
  for (int s = 128; s > 0; s >>= 1) {
    if (tid < s) red[tid] = fmaxf(red[tid], red[tid + s]);
    __syncthreads();
  }
  float scale = fmaxf(red[0], 1e-8f) / 127.f;
  if (sidx >= 0 && tid == 0) scales[sidx] = scale;
  for (int i = tid; i < n; i += 256) {
    float q = rintf(src[i] / scale);             // RNE, matches jnp.round
    q = fminf(fmaxf(q, -128.f), 127.f);
    if (df) df[i] = q * scale;
    else    db[i] = f2b(q);                      // integer in [-128,127]: exact in bf16
  }
}

// ---------------- depthwise 3x3 SAME (f32 math), NCHW in -> frag-tiled bf16 --
// Thread: 4 consecutive x-pixels x 8 channels. Wave: 2 full rows (perfectly
// contiguous float4 row loads). Halo via 2 shuffles/row-channel + edge zeroing.
// NG=2: two gates (z,r) share the input read. NG=1: q gate.
template <int NG, typename TH>
__global__ __launch_bounds__(256, 4) void dwconv_kernel(
    const TH*    __restrict__ src_h,   // 128-ch tensor (h f32 or r*h bf16), NCHW
    const float* __restrict__ src_x,   // 320-ch tensor x, NCHW
    const float* __restrict__ w0, const float* __restrict__ b0,
    const float* __restrict__ w1, const float* __restrict__ b1,
    bf16* __restrict__ out0, bf16* __restrict__ out1)   // frag-tiled
{
  int cg   = blockIdx.x;               // 0..55 (8 channels) == kg
  int b    = blockIdx.z;               // 0..7
  int lane = threadIdx.x & 63;
  int wv   = threadIdx.x >> 6;
  int y    = blockIdx.y * 8 + wv * 2 + (lane >> 5);   // block covers 8 rows
  int x0   = (lane & 31) * 4;
  int c0   = cg * 8;
  bool in_h = (c0 < HIDC);
  const TH*    baseh = src_h + ((size_t)b * HIDC + c0) * HW;
  const float* basex = src_x + ((size_t)b * INPC + (c0 - HIDC)) * HW;

  float acc0[8][4], acc1[8][4];
#pragma unroll
  for (int i = 0; i < 8; i++) {
    int c = c0 + i;
    const TH*    ph = baseh + (size_t)i * HW;
    const float* pf = basex + (size_t)i * HW;
    float a0[4] = {0.f, 0.f, 0.f, 0.f};
    float a1[4] = {0.f, 0.f, 0.f, 0.f};
#pragma unroll
    for (int dy = -1; dy <= 1; dy++) {
      int yy = y + dy;
      bool valid = (unsigned)yy < (unsigned)HH;
      int yc = valid ? yy : (yy < 0 ? 0 : HH - 1);   // clamped addr, zeroed below
      float v[4];
      if (in_h) load4(ph + yc * WWI + x0, v);
      else      load4(pf + yc * WWI + x0, v);
      if (!valid) { v[0] = v[1] = v[2] = v[3] = 0.f; }
      float vL = __shfl_up(v[3], 1);
      if ((lane & 31) == 0) vL = 0.f;                // x = -1 (SAME pad / row edge)
      float vR = __shfl_down(v[0], 1);
      if ((lane & 31) == 31) vR = 0.f;               // x = 128
      int t = (dy + 1) * 3;
      float u0 = w0[c * 9 + t], u1 = w0[c * 9 + t + 1], u2 = w0[c * 9 + t + 2];
      a0[0] += vL   * u0 + v[0] * u1 + v[1] * u2;
      a0[1] += v[0] * u0 + v[1] * u1 + v[2] * u2;
      a0[2] += v[1] * u0 + v[2] * u1 + v[3] * u2;
      a0[3] += v[2] * u0 + v[3] * u1 + vR   * u2;
      if (NG == 2) {
        float s0 = w1[c * 9 + t], s1 = w1[c * 9 + t + 1], s2 = w1[c * 9 + t + 2];
        a1[0] += vL   * s0 + v[0] * s1 + v[1] * s2;
        a1[1] += v[0] * s0 + v[1] * s1 + v[2] * s2;
        a1[2] += v[1] * s0 + v[2] * s1 + v[3] * s2;
        a1[3] += v[2] * s0 + v[3] * s1 + vR   * s2;
      }
    }
    float bb0 = b0[c];
    float bb1 = (NG == 2) ? b1[c] : 0.f;
#pragma unroll
    for (int p = 0; p < 4; p++) {
      acc0[i][p] = a0[p] + bb0;
      if (NG == 2) acc1[i][p] = a1[p] + bb1;
    }
  }
  int pix = y * WWI + x0;
  int nt = pix >> 4, ln = pix & 15;                  // all 4 px share nt
  size_t off = (((size_t)b * NT_PER_B + nt) * KG + cg) * 128 + ln * 8;
#pragma unroll
  for (int p = 0; p < 4; p++) {
    bf16x8 v0, v1;
#pragma unroll
    for (int i = 0; i < 8; i++) {
      v0[i] = (__bf16)acc0[i][p];
      if (NG == 2) v1[i] = (__bf16)acc1[i][p];
    }
    *reinterpret_cast<bf16x8*>(out0 + off + p * 8) = v0;
    if (NG == 2) *reinterpret_cast<bf16x8*>(out1 + off + p * 8) = v1;
  }
}

// ---------------- pointwise 448->128 as MFMA GEMM + fused epilogue ----------
// 64-N tile per block (1024 blocks -> 4+ blocks/CU for latency hiding).
// pre = (sum_k q_int[o][k]*d[n][k]) * scale + bias[o]
// GATE 0: z = sigmoid(pre) -> zout (bf16)
// GATE 1: r = sigmoid(pre) ; rhout = bf16(r * h)
// GATE 2: q = tanh(pre)    ; qout  = f32((1-z)*h + z*q)
template <int GATE>
__global__ __launch_bounds__(256) void pw_kernel(
    const bf16*  __restrict__ dbuf,   // frag-tiled [b][nt][kg][16][8] bf16
    const bf16*  __restrict__ wp,     // [128][448] int8 values as bf16
    const float* __restrict__ bp,     // [128] f32
    const float* __restrict__ scale_p,
    const float* __restrict__ h,      // NCHW f32
    const bf16*  __restrict__ zin,    // bf16 (GATE==2)
    bf16*  __restrict__ zout,         // GATE==0
    bf16*  __restrict__ rhout,        // GATE==1
    float* __restrict__ qout)         // GATE==2
{
  __shared__ bf16 Blds[2048];        // [cell(16)=nt*4+kgl][ln(16)][kj(8)] = 4 KB
  int b    = blockIdx.y;
  int n0   = blockIdx.x * 64;
  int nt0  = blockIdx.x * 4;
  int tid  = threadIdx.x;
  int wave = tid >> 6;
  int lane = tid & 63;
  int quad = lane >> 4;
  int lr   = lane & 15;
  int m0   = wave * 32;              // each wave: 32 M-rows x 64 N
  f32x4 acc[2][4] = {};
  const bf16* dbt = dbuf + ((size_t)b * NT_PER_B + nt0) * (KG * 128);
  float s = *scale_p;

  for (int kk = 0; kk < 14; kk++) {
    // stage B tile: 4 nt x 4 kgl x 128 elems, linear copy, 1 chunk/thread
    {
      int cell = tid >> 4, sub = tid & 15;      // cell = nt*4+kgl
      int nt = cell >> 2, kgl = cell & 3;
      bf16x8 g = *reinterpret_cast<const bf16x8*>(
          dbt + ((size_t)nt * KG + kk * 4 + kgl) * 128 + sub * 8);
      *reinterpret_cast<bf16x8*>(&Blds[tid * 8]) = g;
    }
    __syncthreads();
    int k0 = kk * 32;
    // A frags straight from global (weights 112 KB total, L2-hot)
    bf16x8 a0 = *reinterpret_cast<const bf16x8*>(wp + (size_t)(m0 + lr) * CC + k0 + quad * 8);
    bf16x8 a1 = *reinterpret_cast<const bf16x8*>(wp + (size_t)(m0 + 16 + lr) * CC + k0 + quad * 8);
#pragma unroll
    for (int nf = 0; nf < 4; nf++) {
      bf16x8 bfr = *reinterpret_cast<const bf16x8*>(&Blds[((nf * 4 + quad) * 16 + lr) * 8]);
      acc[0][nf] = __builtin_amdgcn_mfma_f32_16x16x32_bf16(a0, bfr, acc[0][nf], 0, 0, 0);
      acc[1][nf] = __builtin_amdgcn_mfma_f32_16x16x32_bf16(a1, bfr, acc[1][nf], 0, 0, 0);
    }
    __syncthreads();
  }

  // epilogue: C/D layout col(N) = lane&15, row(M) = quad*4 + reg
#pragma unroll
  for (int mf = 0; mf < 2; mf++) {
#pragma unroll
    for (int r = 0; r < 4; r++) {
      int o = m0 + mf * 16 + quad * 4 + r;
      float bias = bp[o];
#pragma unroll
      for (int nf = 0; nf < 4; nf++) {
        int n = n0 + nf * 16 + lr;
        size_t idx = ((size_t)b * HIDC + o) * HW + n;
        float pre = acc[mf][nf][r] * s + bias;
        if (GATE == 0) {
          zout[idx] = f2b(1.f / (1.f + expf(-pre)));
        } else if (GATE == 1) {
          float rv = 1.f / (1.f + expf(-pre));
          rhout[idx] = f2b(rv * h[idx]);
        } else {
          float qv = tanhf(pre);
          float zv = b2f(zin[idx]);
          float hv = h[idx];
          qout[idx] = (1.f - zv) * hv + zv * qv;
        }
      }
    }
  }
}

extern "C" void kernel_launch(void* const* d_in, const int* in_sizes, int n_in,
                              void* d_out, int out_size, void* d_ws, size_t ws_size,
                              hipStream_t stream)
{
  const float* h   = (const float*)d_in[0];
  const float* x   = (const float*)d_in[1];
  const float* wdz = (const float*)d_in[2];
  const float* bdz = (const float*)d_in[3];
  const float* wpz = (const float*)d_in[4];
  const float* bpz = (const float*)d_in[5];
  const float* wdr = (const float*)d_in[6];
  const float* bdr = (const float*)d_in[7];
  const float* wpr = (const float*)d_in[8];
  const float* bpr = (const float*)d_in[9];
  const float* wdq = (const float*)d_in[10];
  const float* bdq = (const float*)d_in[11];
  const float* wpq = (const float*)d_in[12];
  const float* bpq = (const float*)d_in[13];

  char* ws = (char*)d_ws;
  float* qwd    = (float*)ws;                   // [0,4032) z | [4096,8128) r | [8192,12224) q
  float* scales = qwd + 12288;                  // 3 floats
  bf16*  qwp    = (bf16*)(ws + 65536);          // 3 x 57344 bf16 (int8 values)
  const size_t DBUF_ELEMS = (size_t)BB * NT_PER_B * KG * 128;  // 29,360,128
  bf16*  dz   = (bf16*)(ws + (1 << 20));                       // 58.7 MB
  bf16*  dr   = dz + DBUF_ELEMS;                               // 58.7 MB
  bf16*  zbuf = dr + DBUF_ELEMS;                               // 16.8 MB (bf16 now)
  bf16*  rh   = zbuf + (size_t)BB * HIDC * HW;                 // 16.8 MB

  quant_kernel<<<6, 256, 0, stream>>>(wdz, wpz, wdr, wpr, wdq, wpq, qwd, qwp, scales);

  dim3 dgrid(56, 8, 8);    // (cgroup, y-octet, batch)
  dwconv_kernel<2, float><<<dgrid, 256, 0, stream>>>(h, x, qwd, bdz, qwd + 4096, bdr, dz, dr);

  dim3 pgrid(128, 8);      // (64-wide n-tile, batch)
  pw_kernel<0><<<pgrid, 256, 0, stream>>>(dz, qwp, bpz, scales + 0, nullptr, nullptr,
                                          zbuf, nullptr, nullptr);
  pw_kernel<1><<<pgrid, 256, 0, stream>>>(dr, qwp + HIDC * CC, bpr, scales + 1, h, nullptr,
                                          nullptr, rh, nullptr);

  dwconv_kernel<1, bf16><<<dgrid, 256, 0, stream>>>(rh, x, qwd + 8192, bdq, nullptr, nullptr,
                                                    dz, nullptr);

  pw_kernel<2><<<pgrid, 256, 0, stream>>>(dz, qwp + 2 * HIDC * CC, bpq, scales + 2, h, zbuf,
                                          nullptr, nullptr, (float*)d_out);
}

// Round 5
// 581.216 us; speedup vs baseline: 1.5355x; 1.0262x over previous
//
#include <hip/hip_runtime.h>
#include <hip/hip_bf16.h>

#define BB  8
#define HIDC 128
#define INPC 320
#define CC  448
#define HH  64
#define WWI 128
#define HW  8192   // 64*128
#define NT_PER_B 512        // HW/16
#define KG  56              // CC/8
// frag-tiled dbuf: [b][nt][kg][ln(16)][kj(8)] bf16; elem off = ((b*512+nt)*56+kg)*128 + ln*8 + kj

using bf16   = __hip_bfloat16;
using bf16x8 = __attribute__((ext_vector_type(8))) __bf16;
using bf16x4 = __attribute__((ext_vector_type(4))) __bf16;
using f32x4  = __attribute__((ext_vector_type(4))) float;

__device__ __forceinline__ float b2f(bf16 v) { return __bfloat162float(v); }
__device__ __forceinline__ bf16  f2b(float v) { return __float2bfloat16(v); }

__device__ __forceinline__ void load4(const float* p, float v[4]) {
  f32x4 t = *reinterpret_cast<const f32x4*>(p);     // 16B-aligned (x0 mult of 4)
  v[0] = t[0]; v[1] = t[1]; v[2] = t[2]; v[3] = t[3];
}
__device__ __forceinline__ void load4(const bf16* p, float v[4]) {
  bf16x4 t = *reinterpret_cast<const bf16x4*>(p);   // 8B-aligned
  v[0] = (float)t[0]; v[1] = (float)t[1]; v[2] = (float)t[2]; v[3] = (float)t[3];
}

// ---------------- per-tensor symmetric int8 fake-quant ----------------
// scale = max(max|w|,1e-8)/127 ; q = clip(rint(w/scale),-128,127)
// dw gates: store q*scale as f32. pw gates: store q as bf16 INTEGER (exact),
// scale applied in the GEMM epilogue -> no bf16 rounding on weights.
__global__ __launch_bounds__(256) void quant_kernel(
    const float* wdz, const float* wpz, const float* wdr, const float* wpr,
    const float* wdq, const float* wpq, float* qwd, bf16* qwp, float* scales)
{
  const float* src = nullptr; int n = 0; float* df = nullptr; bf16* db = nullptr;
  int sidx = -1;
  switch (blockIdx.x) {
    case 0: src = wdz; n = CC * 9;    df = qwd;                 break;
    case 1: src = wpz; n = HIDC * CC; db = qwp;                 sidx = 0; break;
    case 2: src = wdr; n = CC * 9;    df = qwd + 4096;          break;
    case 3: src = wpr; n = HIDC * CC; db = qwp + HIDC * CC;     sidx = 1; break;
    case 4: src = wdq; n = CC * 9;    df = qwd + 8192;          break;
    case 5: src = wpq; n = HIDC * CC; db = qwp + 2 * HIDC * CC; sidx = 2; break;
  }
  __shared__ float red[256];
  int tid = threadIdx.x;
  float m = 0.f;
  for (int i = tid; i < n; i += 256) m = fmaxf(m, fabsf(src[i]));
  red[tid] = m; __syncthreads();
  for (int s = 128; s > 0; s >>= 1) {
    if (tid < s) red[tid] = fmaxf(red[tid], red[tid + s]);
    __syncthreads();
  }
  float scale = fmaxf(red[0], 1e-8f) / 127.f;
  if (sidx >= 0 && tid == 0) scales[sidx] = scale;
  for (int i = tid; i < n; i += 256) {
    float q = rintf(src[i] / scale);             // RNE, matches jnp.round
    q = fminf(fmaxf(q, -128.f), 127.f);
    if (df) df[i] = q * scale;
    else    db[i] = f2b(q);                      // integer in [-128,127]: exact in bf16
  }
}

// ---------------- depthwise 3x3 SAME (f32 math), NCHW in -> frag-tiled bf16 --
// Thread: 4 consecutive x-pixels x 8 channels (coalesced float4 row loads,
// shuffle halos). Results round-trip a per-wave LDS staging buffer so each
// GLOBAL store instruction covers 256 B-contiguous segments per 16 lanes
// (round-3 pattern, measured clean 114688 KB; round-4's 16B-at-stride-64B
// pattern measured 2.6x write amplification).
template <int NG, typename TH>
__global__ __launch_bounds__(256, 4) void dwconv_kernel(
    const TH*    __restrict__ src_h,   // 128-ch tensor (h f32 or r*h bf16), NCHW
    const float* __restrict__ src_x,   // 320-ch tensor x, NCHW
    const float* __restrict__ w0, const float* __restrict__ b0,
    const float* __restrict__ w1, const float* __restrict__ b1,
    bf16* __restrict__ out0, bf16* __restrict__ out1)   // frag-tiled
{
  // [wave][gate][row(2)][p(4)][lam(32)][8ch] bf16 : 32 KB (NG=2) / 16 KB (NG=1)
  __shared__ __align__(16) bf16 stg[4][NG][2][4][32][8];

  int cg   = blockIdx.x;               // 0..55 (8 channels) == kg
  int b    = blockIdx.z;               // 0..7
  int lane = threadIdx.x & 63;
  int w    = threadIdx.x >> 6;
  int r    = lane >> 5;
  int lam  = lane & 31;
  int y    = blockIdx.y * 8 + w * 2 + r;   // block covers 8 rows
  int x0   = lam * 4;
  int c0   = cg * 8;
  bool in_h = (c0 < HIDC);
  const TH*    baseh = src_h + ((size_t)b * HIDC + c0) * HW;
  const float* basex = src_x + ((size_t)b * INPC + (c0 - HIDC)) * HW;

  float acc0[8][4], acc1[8][4];
#pragma unroll
  for (int i = 0; i < 8; i++) {
    int c = c0 + i;
    const TH*    ph = baseh + (size_t)i * HW;
    const float* pf = basex + (size_t)i * HW;
    float a0[4] = {0.f, 0.f, 0.f, 0.f};
    float a1[4] = {0.f, 0.f, 0.f, 0.f};
#pragma unroll
    for (int dy = -1; dy <= 1; dy++) {
      int yy = y + dy;
      bool valid = (unsigned)yy < (unsigned)HH;
      int yc = valid ? yy : (yy < 0 ? 0 : HH - 1);   // clamped addr, zeroed below
      float v[4];
      if (in_h) load4(ph + yc * WWI + x0, v);
      else      load4(pf + yc * WWI + x0, v);
      if (!valid) { v[0] = v[1] = v[2] = v[3] = 0.f; }
      float vL = __shfl_up(v[3], 1);
      if (lam == 0) vL = 0.f;                        // x = -1 (SAME pad / row edge)
      float vR = __shfl_down(v[0], 1);
      if (lam == 31) vR = 0.f;                       // x = 128
      int t = (dy + 1) * 3;
      float u0 = w0[c * 9 + t], u1 = w0[c * 9 + t + 1], u2 = w0[c * 9 + t + 2];
      a0[0] += vL   * u0 + v[0] * u1 + v[1] * u2;
      a0[1] += v[0] * u0 + v[1] * u1 + v[2] * u2;
      a0[2] += v[1] * u0 + v[2] * u1 + v[3] * u2;
      a0[3] += v[2] * u0 + v[3] * u1 + vR   * u2;
      if (NG == 2) {
        float s0 = w1[c * 9 + t], s1 = w1[c * 9 + t + 1], s2 = w1[c * 9 + t + 2];
        a1[0] += vL   * s0 + v[0] * s1 + v[1] * s2;
        a1[1] += v[0] * s0 + v[1] * s1 + v[2] * s2;
        a1[2] += v[1] * s0 + v[2] * s1 + v[3] * s2;
        a1[3] += v[2] * s0 + v[3] * s1 + vR   * s2;
      }
    }
    float bb0 = b0[c];
    float bb1 = (NG == 2) ? b1[c] : 0.f;
#pragma unroll
    for (int p = 0; p < 4; p++) {
      acc0[i][p] = a0[p] + bb0;
      if (NG == 2) acc1[i][p] = a1[p] + bb1;
    }
  }

  // stage to LDS: write layout [p][lam] -> contiguous 512 B per half-wave instr
#pragma unroll
  for (int p = 0; p < 4; p++) {
    bf16x8 v0, v1;
#pragma unroll
    for (int i = 0; i < 8; i++) {
      v0[i] = (__bf16)acc0[i][p];
      if (NG == 2) v1[i] = (__bf16)acc1[i][p];
    }
    *reinterpret_cast<bf16x8*>(&stg[w][0][r][p][lam][0]) = v0;
    if (NG == 2) *reinterpret_cast<bf16x8*>(&stg[w][1][r][p][lam][0]) = v1;
  }
  // wave-local round-trip: no __syncthreads needed (compiler inserts lgkmcnt)

  // read back in global-coalesced order: instr j covers 4 cells x 256 B,
  // each 16-lane group writes one full 256 B (2-line) contiguous segment.
#pragma unroll
  for (int j = 0; j < 4; j++) {
    int r2   = j >> 1;
    int cell = (j & 1) * 4 + (lane >> 4);        // 0..7 within the row
    int ln   = lane & 15;
    int px   = cell * 16 + ln;                   // x-coordinate 0..127
    int yr   = blockIdx.y * 8 + w * 2 + r2;
    size_t off = (((size_t)b * NT_PER_B + yr * 8 + cell) * KG + cg) * 128 + ln * 8;
    bf16x8 t0 = *reinterpret_cast<bf16x8*>(&stg[w][0][r2][px & 3][px >> 2][0]);
    *reinterpret_cast<bf16x8*>(out0 + off) = t0;
    if (NG == 2) {
      bf16x8 t1 = *reinterpret_cast<bf16x8*>(&stg[w][1][r2][px & 3][px >> 2][0]);
      *reinterpret_cast<bf16x8*>(out1 + off) = t1;
    }
  }
}

// ---------------- pointwise 448->128 as MFMA GEMM + fused epilogue ----------
// 64-N tile per block (1024 blocks -> 4+ blocks/CU for latency hiding).
// pre = (sum_k q_int[o][k]*d[n][k]) * scale + bias[o]
// GATE 0: z = sigmoid(pre) -> zout (bf16)
// GATE 1: r = sigmoid(pre) ; rhout = bf16(r * h)
// GATE 2: q = tanh(pre)    ; qout  = f32((1-z)*h + z*q)
template <int GATE>
__global__ __launch_bounds__(256) void pw_kernel(
    const bf16*  __restrict__ dbuf,   // frag-tiled [b][nt][kg][16][8] bf16
    const bf16*  __restrict__ wp,     // [128][448] int8 values as bf16
    const float* __restrict__ bp,     // [128] f32
    const float* __restrict__ scale_p,
    const float* __restrict__ h,      // NCHW f32
    const bf16*  __restrict__ zin,    // bf16 (GATE==2)
    bf16*  __restrict__ zout,         // GATE==0
    bf16*  __restrict__ rhout,        // GATE==1
    float* __restrict__ qout)         // GATE==2
{
  __shared__ bf16 Blds[2048];        // [cell(16)=nt*4+kgl][ln(16)][kj(8)] = 4 KB
  int b    = blockIdx.y;
  int n0   = blockIdx.x * 64;
  int nt0  = blockIdx.x * 4;
  int tid  = threadIdx.x;
  int wave = tid >> 6;
  int lane = tid & 63;
  int quad = lane >> 4;
  int lr   = lane & 15;
  int m0   = wave * 32;              // each wave: 32 M-rows x 64 N
  f32x4 acc[2][4] = {};
  const bf16* dbt = dbuf + ((size_t)b * NT_PER_B + nt0) * (KG * 128);
  float s = *scale_p;

  for (int kk = 0; kk < 14; kk++) {
    // stage B tile: 4 nt x 4 kgl x 128 elems, linear copy, 1 chunk/thread
    {
      int cell = tid >> 4, sub = tid & 15;      // cell = nt*4+kgl
      int nt = cell >> 2, kgl = cell & 3;
      bf16x8 g = *reinterpret_cast<const bf16x8*>(
          dbt + ((size_t)nt * KG + kk * 4 + kgl) * 128 + sub * 8);
      *reinterpret_cast<bf16x8*>(&Blds[tid * 8]) = g;
    }
    __syncthreads();
    int k0 = kk * 32;
    // A frags straight from global (weights 112 KB total, L2-hot)
    bf16x8 a0 = *reinterpret_cast<const bf16x8*>(wp + (size_t)(m0 + lr) * CC + k0 + quad * 8);
    bf16x8 a1 = *reinterpret_cast<const bf16x8*>(wp + (size_t)(m0 + 16 + lr) * CC + k0 + quad * 8);
#pragma unroll
    for (int nf = 0; nf < 4; nf++) {
      bf16x8 bfr = *reinterpret_cast<const bf16x8*>(&Blds[((nf * 4 + quad) * 16 + lr) * 8]);
      acc[0][nf] = __builtin_amdgcn_mfma_f32_16x16x32_bf16(a0, bfr, acc[0][nf], 0, 0, 0);
      acc[1][nf] = __builtin_amdgcn_mfma_f32_16x16x32_bf16(a1, bfr, acc[1][nf], 0, 0, 0);
    }
    __syncthreads();
  }

  // epilogue: C/D layout col(N) = lane&15, row(M) = quad*4 + reg
#pragma unroll
  for (int mf = 0; mf < 2; mf++) {
#pragma unroll
    for (int r = 0; r < 4; r++) {
      int o = m0 + mf * 16 + quad * 4 + r;
      float bias = bp[o];
#pragma unroll
      for (int nf = 0; nf < 4; nf++) {
        int n = n0 + nf * 16 + lr;
        size_t idx = ((size_t)b * HIDC + o) * HW + n;
        float pre = acc[mf][nf][r] * s + bias;
        if (GATE == 0) {
          zout[idx] = f2b(1.f / (1.f + expf(-pre)));
        } else if (GATE == 1) {
          float rv = 1.f / (1.f + expf(-pre));
          rhout[idx] = f2b(rv * h[idx]);
        } else {
          float qv = tanhf(pre);
          float zv = b2f(zin[idx]);
          float hv = h[idx];
          qout[idx] = (1.f - zv) * hv + zv * qv;
        }
      }
    }
  }
}

extern "C" void kernel_launch(void* const* d_in, const int* in_sizes, int n_in,
                              void* d_out, int out_size, void* d_ws, size_t ws_size,
                              hipStream_t stream)
{
  const float* h   = (const float*)d_in[0];
  const float* x   = (const float*)d_in[1];
  const float* wdz = (const float*)d_in[2];
  const float* bdz = (const float*)d_in[3];
  const float* wpz = (const float*)d_in[4];
  const float* bpz = (const float*)d_in[5];
  const float* wdr = (const float*)d_in[6];
  const float* bdr = (const float*)d_in[7];
  const float* wpr = (const float*)d_in[8];
  const float* bpr = (const float*)d_in[9];
  const float* wdq = (const float*)d_in[10];
  const float* bdq = (const float*)d_in[11];
  const float* wpq = (const float*)d_in[12];
  const float* bpq = (const float*)d_in[13];

  char* ws = (char*)d_ws;
  float* qwd    = (float*)ws;                   // [0,4032) z | [4096,8128) r | [8192,12224) q
  float* scales = qwd + 12288;                  // 3 floats
  bf16*  qwp    = (bf16*)(ws + 65536);          // 3 x 57344 bf16 (int8 values)
  const size_t DBUF_ELEMS = (size_t)BB * NT_PER_B * KG * 128;  // 29,360,128
  bf16*  dz   = (bf16*)(ws + (1 << 20));                       // 58.7 MB
  bf16*  dr   = dz + DBUF_ELEMS;                               // 58.7 MB
  bf16*  zbuf = dr + DBUF_ELEMS;                               // 16.8 MB (bf16)
  bf16*  rh   = zbuf + (size_t)BB * HIDC * HW;                 // 16.8 MB

  quant_kernel<<<6, 256, 0, stream>>>(wdz, wpz, wdr, wpr, wdq, wpq, qwd, qwp, scales);

  dim3 dgrid(56, 8, 8);    // (cgroup, y-octet, batch)
  dwconv_kernel<2, float><<<dgrid, 256, 0, stream>>>(h, x, qwd, bdz, qwd + 4096, bdr, dz, dr);

  dim3 pgrid(128, 8);      // (64-wide n-tile, batch)
  pw_kernel<0><<<pgrid, 256, 0, stream>>>(dz, qwp, bpz, scales + 0, nullptr, nullptr,
                                          zbuf, nullptr, nullptr);
  pw_kernel<1><<<pgrid, 256, 0, stream>>>(dr, qwp + HIDC * CC, bpr, scales + 1, h, nullptr,
                                          nullptr, rh, nullptr);

  dwconv_kernel<1, bf16><<<dgrid, 256, 0, stream>>>(rh, x, qwd + 8192, bdq, nullptr, nullptr,
                                                    dz, nullptr);

  pw_kernel<2><<<pgrid, 256, 0, stream>>>(dz, qwp + 2 * HIDC * CC, bpq, scales + 2, h, zbuf,
                                          nullptr, nullptr, (float*)d_out);
}